// Round 14
// baseline (480.584 us; speedup 1.0000x reference)
//
#include <hip/hip_runtime.h>
#include <cstdint>

#define LEAKY 0.2f
#define LN_EPS 1e-5f

typedef __attribute__((ext_vector_type(8))) short short8;   // 8 x bf16 (4 VGPR)
typedef __attribute__((ext_vector_type(4))) float f32x4;    // MFMA accum
typedef __attribute__((ext_vector_type(2))) float f32x2;
typedef __attribute__((ext_vector_type(2))) uint u32x2;

__device__ __forceinline__ ushort bf16_rne(float x) {
    unsigned u = __float_as_uint(x);
    unsigned r = (u + 0x7fffu + ((u >> 16) & 1u)) >> 16;
    return (ushort)r;
}
__device__ __forceinline__ float bf16_to_f(ushort h) {
    return __uint_as_float(((unsigned)h) << 16);
}
__device__ __forceinline__ f32x4 unpk4(u32x2 u) {
    f32x4 r;
    r.x = __uint_as_float(u.x << 16);
    r.y = __uint_as_float(u.x & 0xffff0000u);
    r.z = __uint_as_float(u.y << 16);
    r.w = __uint_as_float(u.y & 0xffff0000u);
    return r;
}

// ---------------------------------------------------------------------------
// CSR build, XCD-partitioned (round-12 win: no cross-XCD cacheline ping-pong)
// ---------------------------------------------------------------------------
__global__ void hist_part(const int* __restrict__ ei, int er, int etot, int n,
                          int* __restrict__ deg) {
    const int xcd = blockIdx.x & 7;
    const int lo = (int)((long long)n * xcd >> 3);
    const int hi = (int)((long long)n * (xcd + 1) >> 3);
    const int stride = (gridDim.x >> 3) * blockDim.x;
    for (int e = (blockIdx.x >> 3) * blockDim.x + threadIdx.x; e < etot;
         e += stride) {
        int dst = (e < er) ? ei[er + e] : (e - er);
        if (dst >= lo && dst < hi) atomicAdd(&deg[dst], 1);
    }
}

__global__ void fill_part(const int* __restrict__ ei, int er, int etot, int n,
                          int* __restrict__ woff, int* __restrict__ colv) {
    const int xcd = blockIdx.x & 7;
    const int lo = (int)((long long)n * xcd >> 3);
    const int hi = (int)((long long)n * (xcd + 1) >> 3);
    const int stride = (gridDim.x >> 3) * blockDim.x;
    for (int e = (blockIdx.x >> 3) * blockDim.x + threadIdx.x; e < etot;
         e += stride) {
        int dst = (e < er) ? ei[er + e] : (e - er);
        if (dst >= lo && dst < hi) {
            int src = (e < er) ? ei[e] : dst;
            int pos = atomicAdd(&woff[dst], 1);
            colv[pos] = src;
        }
    }
}

__global__ __launch_bounds__(1024) void scanA(const int* __restrict__ deg,
                                              int* __restrict__ escan,
                                              int* __restrict__ bsum, int n) {
    __shared__ int wsum[16], wpre[16];
    const int lane = threadIdx.x & 63, wv = threadIdx.x >> 6;
    const int i = blockIdx.x * 1024 + threadIdx.x;
    int v = (i < n) ? deg[i] : 0;
    int x = v;
#pragma unroll
    for (int off = 1; off < 64; off <<= 1) {
        int y = __shfl_up(x, off, 64);
        if (lane >= off) x += y;
    }
    if (lane == 63) wsum[wv] = x;
    __syncthreads();
    if (wv == 0) {
        int s = (lane < 16) ? wsum[lane] : 0;
#pragma unroll
        for (int off = 1; off < 16; off <<= 1) {
            int y = __shfl_up(s, off, 64);
            if (lane >= off) s += y;
        }
        if (lane < 16) wpre[lane] = s;
    }
    __syncthreads();
    int excl = x - v + (wv ? wpre[wv - 1] : 0);
    if (i < n) escan[i] = excl;
    if (threadIdx.x == 1023) bsum[blockIdx.x] = wpre[15];
}

__global__ __launch_bounds__(1024) void scanB(const int* __restrict__ bsum,
                                              int* __restrict__ bpre, int nb,
                                              int* __restrict__ offs, int n) {
    __shared__ int wsum[16], wpre[16];
    const int lane = threadIdx.x & 63, wv = threadIdx.x >> 6;
    const int i = threadIdx.x;
    int v = (i < nb) ? bsum[i] : 0;
    int x = v;
#pragma unroll
    for (int off = 1; off < 64; off <<= 1) {
        int y = __shfl_up(x, off, 64);
        if (lane >= off) x += y;
    }
    if (lane == 63) wsum[wv] = x;
    __syncthreads();
    if (wv == 0) {
        int s = (lane < 16) ? wsum[lane] : 0;
#pragma unroll
        for (int off = 1; off < 16; off <<= 1) {
            int y = __shfl_up(s, off, 64);
            if (lane >= off) s += y;
        }
        if (lane < 16) wpre[lane] = s;
    }
    __syncthreads();
    if (i < nb) bpre[i] = x - v + (wv ? wpre[wv - 1] : 0);
    if (threadIdx.x == 1023) offs[n] = wpre[15];
}

__global__ void scanC(const int* __restrict__ escan, const int* __restrict__ bpre,
                      int* __restrict__ offs, int* __restrict__ woff, int n) {
    int i = blockIdx.x * 256 + threadIdx.x;
    if (i >= n) return;
    int o = escan[i] + bpre[i >> 10];
    offs[i] = o;
    woff[i] = o;
}

// ---------------------------------------------------------------------------
// Both layers' W -> per-MFMA-fragment bf16 hi/lo layout (one dispatch).
// ---------------------------------------------------------------------------
__global__ void cvt_w2(const float* __restrict__ Wl0, const float* __restrict__ Wr0,
                       const float* __restrict__ Wl1, const float* __restrict__ Wr1,
                       ushort* __restrict__ Whi, ushort* __restrict__ Wlo) {
    int t = blockIdx.x * 256 + threadIdx.x;     // 0..65535
    int layer = t >> 15;
    int i = t & 32767;
    int colblk = i >> 11;
    int ks = (i >> 9) & 3;
    int lane = (i >> 3) & 63;
    int j = i & 7;
    int col = colblk * 16 + (lane & 15);
    int k = ks * 32 + (lane >> 4) * 8 + j;
    const float* Wl = layer ? Wl1 : Wl0;
    const float* Wr = layer ? Wr1 : Wr0;
    float v = (col < 128) ? Wl[(size_t)k * 128 + col]
                          : Wr[(size_t)k * 128 + (col - 128)];
    ushort h = bf16_rne(v);
    Whi[t] = h;
    Wlo[t] = bf16_rne(v - bf16_to_f(h));
}

// ---------------------------------------------------------------------------
// Dual GEMM. A-input either fp32 (split-bf16, 3 MFMA) or packed bf16
// (exact, 2 MFMA + half the read). Output packed bf16 pairs.
// ---------------------------------------------------------------------------
template <bool ABF16>
__global__ __launch_bounds__(256) void gemm_mfma(
    const void* __restrict__ Xin,
    const ushort* __restrict__ Wfhi, const ushort* __restrict__ Wflo,
    uint* __restrict__ Olb, uint* __restrict__ Orb, int nrows) {
    __shared__ float4 xs[64 * 32];              // 32 KiB (fp32) / 16 KiB used (bf16)
    const int t = threadIdx.x;
    const int wave = t >> 6, lane = t & 63;
    const int m0 = blockIdx.x * 64;
    if (ABF16) {
        const uint4* Xv = (const uint4*)Xin + (size_t)m0 * 16;
        uint4* xsb = (uint4*)xs;
#pragma unroll
        for (int i = 0; i < 4; ++i) {
            int idx = i * 256 + t;
            int row = idx >> 4, kc = idx & 15;
            uint4 v = {0u, 0u, 0u, 0u};
            if (m0 + row < nrows) v = Xv[idx];
            xsb[row * 16 + (kc ^ (row & 7))] = v;
        }
    } else {
        const float4* Xv = (const float4*)Xin + (size_t)m0 * 32;
#pragma unroll
        for (int i = 0; i < 8; ++i) {
            int idx = i * 256 + t;
            int row = idx >> 5, kc = idx & 31;
            float4 v = {0.f, 0.f, 0.f, 0.f};
            if (m0 + row < nrows) v = Xv[idx];
            xs[row * 32 + (kc ^ (row & 7))] = v;
        }
    }
    __syncthreads();

    const int lrow = lane & 15;
    const int lkc = (lane >> 4) * 2;
    f32x4 acc[4][4];
#pragma unroll
    for (int mt = 0; mt < 4; ++mt)
#pragma unroll
        for (int nt = 0; nt < 4; ++nt) acc[mt][nt] = (f32x4){0.f, 0.f, 0.f, 0.f};

#pragma unroll 1
    for (int ks = 0; ks < 4; ++ks) {
        short8 ahi[4], alo[4];
#pragma unroll
        for (int mt = 0; mt < 4; ++mt) {
            const int row = mt * 16 + lrow;
            if (ABF16) {
                const int slot = ks * 4 + (lane >> 4);
                uint4 w = ((const uint4*)xs)[row * 16 + (slot ^ (row & 7))];
                ahi[mt] = *(const short8*)&w;
            } else {
                const int kc0 = ks * 8 + lkc;
                float4 v0 = xs[row * 32 + (kc0 ^ (row & 7))];
                float4 v1 = xs[row * 32 + ((kc0 + 1) ^ (row & 7))];
                float e[8];
                e[0] = v0.x; e[1] = v0.y; e[2] = v0.z; e[3] = v0.w;
                e[4] = v1.x; e[5] = v1.y; e[6] = v1.z; e[7] = v1.w;
#pragma unroll
                for (int j = 0; j < 8; ++j) {
                    ushort h = (ushort)(__float_as_uint(e[j]) >> 16);  // trunc split
                    ahi[mt][j] = (short)h;
                    alo[mt][j] = (short)bf16_rne(e[j] - bf16_to_f(h));
                }
            }
        }
#pragma unroll
        for (int nt = 0; nt < 4; ++nt) {
            size_t off = (((size_t)(wave * 4 + nt) * 4 + ks) * 64 + lane) * 8;
            short8 bhi = *(const short8*)&Wfhi[off];
            short8 blo = *(const short8*)&Wflo[off];
#pragma unroll
            for (int mt = 0; mt < 4; ++mt) {
                if (!ABF16)
                    acc[mt][nt] = __builtin_amdgcn_mfma_f32_16x16x32_bf16(
                        alo[mt], bhi, acc[mt][nt], 0, 0, 0);
                acc[mt][nt] = __builtin_amdgcn_mfma_f32_16x16x32_bf16(
                    ahi[mt], blo, acc[mt][nt], 0, 0, 0);
                acc[mt][nt] = __builtin_amdgcn_mfma_f32_16x16x32_bf16(
                    ahi[mt], bhi, acc[mt][nt], 0, 0, 0);
            }
        }
    }
    // Epilogue: C/D frag col=lane&15, row=(lane>>4)*4+i; shfl_xor(1) pairs cols.
    uint* __restrict__ O = (wave < 2) ? Olb : Orb;
    const int cbase = (wave * 64) & 127;
    const int crow0 = (lane >> 4) * 4;
    const bool evn = (lane & 1) == 0;
#pragma unroll
    for (int mt = 0; mt < 4; ++mt) {
#pragma unroll
        for (int i = 0; i < 4; ++i) {
            const int row = m0 + mt * 16 + crow0 + i;
#pragma unroll
            for (int nt = 0; nt < 4; ++nt) {
                float val = acc[mt][nt][i];
                float pv = __shfl_xor(val, 1);
                uint pk = (uint)bf16_rne(val) | ((uint)bf16_rne(pv) << 16);
                if (evn && row < nrows) {
                    const int col = cbase + nt * 16 + lrow;
                    O[(size_t)row * 64 + (col >> 1)] = pk;
                }
            }
        }
    }
}

// ---------------------------------------------------------------------------
// Fused GATv2 agg + bias + ELU + residual + LayerNorm.
// TWO nodes per wave: lanes 0-31 = node 2p, lanes 32-63 = node 2p+1; each
// lane owns 4 features (uint2 / f32x4). Halves the per-edge wave-instruction
// count (round-13 measured ~48/edge, VALU-bound). Head reduce = 2 shuffles
// (4 lanes/head); LN reduce = 5 shuffles (masks <32 stay in-half). Edge-count
// imbalance handled by predication (clamped colv index; every node has a
// self-loop so e1-1 is always valid).
// ---------------------------------------------------------------------------
template <bool RBF16, bool OBF16>
__global__ __launch_bounds__(256) void gat_agg(
    const uint* __restrict__ xl, const uint* __restrict__ xr,
    const int* __restrict__ offs, const int* __restrict__ colv,
    const float* __restrict__ att,
    const float* __restrict__ bias, const float* __restrict__ gamma,
    const float* __restrict__ beta, const void* __restrict__ resid,
    void* __restrict__ out, int nnode) {
    const int lane = threadIdx.x & 63;
    const int hl = lane & 31;                 // lane within half
    const int half = lane >> 5;               // 0 = even node, 1 = odd node
    const int wave0 = blockIdx.x * 4 + (threadIdx.x >> 6);
    const int wstride = gridDim.x * 4;
    const int npair = (nnode + 1) >> 1;
    const f32x4 att4 = ((const f32x4*)att)[hl];
    const f32x4 b4 = ((const f32x4*)bias)[hl];
    const f32x4 g4 = ((const f32x4*)gamma)[hl];
    const f32x4 be4 = ((const f32x4*)beta)[hl];
    const u32x2* __restrict__ xl2 = (const u32x2*)xl;
    for (int p = wave0; p < npair; p += wstride) {
        const int node = p * 2 + half;
        const int nodec = node < nnode ? node : nnode - 1;
        const u32x2 xru = __builtin_nontemporal_load(
            (const u32x2*)xr + (size_t)nodec * 32 + hl);
        const f32x4 xr4 = unpk4(xru);
        float den = 0.f;
        f32x4 acc = {0.f, 0.f, 0.f, 0.f};
        int e = offs[nodec];
        const int e1 = offs[nodec + 1];
        const int e1m = e1 - 1;
        int deg = e1 - e;
        int mdeg = max(deg, __shfl_xor(deg, 32));   // cross-half max
        int niter = (mdeg + 3) >> 2;
        for (int it = 0; it < niter; ++it) {
            int ek0 = min(e, e1m), ek1 = min(e + 1, e1m);
            int ek2 = min(e + 2, e1m), ek3 = min(e + 3, e1m);
            int s0 = colv[ek0], s1 = colv[ek1], s2 = colv[ek2], s3 = colv[ek3];
            u32x2 u0 = xl2[(size_t)s0 * 32 + hl];
            u32x2 u1 = xl2[(size_t)s1 * 32 + hl];
            u32x2 u2 = xl2[(size_t)s2 * 32 + hl];
            u32x2 u3 = xl2[(size_t)s3 * 32 + hl];
            f32x4 a0 = unpk4(u0), a1 = unpk4(u1), a2 = unpk4(u2), a3 = unpk4(u3);
            f32x4 m0 = a0 + xr4, m1 = a1 + xr4, m2 = a2 + xr4, m3 = a3 + xr4;
            f32x4 l0 = m0 * LEAKY, l1 = m1 * LEAKY;
            f32x4 l2 = m2 * LEAKY, l3 = m3 * LEAKY;
            m0.x = fmaxf(m0.x, l0.x); m0.y = fmaxf(m0.y, l0.y);
            m0.z = fmaxf(m0.z, l0.z); m0.w = fmaxf(m0.w, l0.w);
            m1.x = fmaxf(m1.x, l1.x); m1.y = fmaxf(m1.y, l1.y);
            m1.z = fmaxf(m1.z, l1.z); m1.w = fmaxf(m1.w, l1.w);
            m2.x = fmaxf(m2.x, l2.x); m2.y = fmaxf(m2.y, l2.y);
            m2.z = fmaxf(m2.z, l2.z); m2.w = fmaxf(m2.w, l2.w);
            m3.x = fmaxf(m3.x, l3.x); m3.y = fmaxf(m3.y, l3.y);
            m3.z = fmaxf(m3.z, l3.z); m3.w = fmaxf(m3.w, l3.w);
            f32x4 t0 = m0 * att4, t1 = m1 * att4, t2 = m2 * att4, t3 = m3 * att4;
            float p0 = (t0.x + t0.y) + (t0.z + t0.w);
            float p1 = (t1.x + t1.y) + (t1.z + t1.w);
            float p2 = (t2.x + t2.y) + (t2.z + t2.w);
            float p3 = (t3.x + t3.y) + (t3.z + t3.w);
            p0 += __shfl_xor(p0, 1); p0 += __shfl_xor(p0, 2);   // 4-lane head sum
            p1 += __shfl_xor(p1, 1); p1 += __shfl_xor(p1, 2);
            p2 += __shfl_xor(p2, 1); p2 += __shfl_xor(p2, 2);
            p3 += __shfl_xor(p3, 1); p3 += __shfl_xor(p3, 2);
            float ex0 = (e < e1) ? __expf(p0) : 0.f;
            float ex1 = (e + 1 < e1) ? __expf(p1) : 0.f;
            float ex2 = (e + 2 < e1) ? __expf(p2) : 0.f;
            float ex3 = (e + 3 < e1) ? __expf(p3) : 0.f;
            den += (ex0 + ex1) + (ex2 + ex3);
            acc += a0 * ex0;
            acc += a1 * ex1;
            acc += a2 * ex2;
            acc += a3 * ex3;
            e += 4;
        }
        const float inv_den = 1.f / den;
        f32x4 v = acc * inv_den + b4;
        v.x = v.x > 0.f ? v.x : expm1f(v.x);     // ELU (alpha=1)
        v.y = v.y > 0.f ? v.y : expm1f(v.y);
        v.z = v.z > 0.f ? v.z : expm1f(v.z);
        v.w = v.w > 0.f ? v.w : expm1f(v.w);
        f32x4 r4;
        if (RBF16) {
            u32x2 ru = __builtin_nontemporal_load(
                (const u32x2*)resid + (size_t)nodec * 32 + hl);
            r4 = unpk4(ru);
        } else {
            r4 = __builtin_nontemporal_load(
                (const f32x4*)resid + (size_t)nodec * 32 + hl);
        }
        f32x4 tv = v + r4;
        float s = (tv.x + tv.y) + (tv.z + tv.w);
        float ss = (tv.x * tv.x + tv.y * tv.y) + (tv.z * tv.z + tv.w * tv.w);
#pragma unroll
        for (int m = 1; m < 32; m <<= 1) {       // 32-lane (in-half) LN reduce
            s += __shfl_xor(s, m);
            ss += __shfl_xor(ss, m);
        }
        const float mu = s * 0.0078125f;
        const float var = ss * 0.0078125f - mu * mu;
        const float iv = rsqrtf(var + LN_EPS);
        f32x4 o = (tv - mu) * iv * g4 + be4;
        if (node < nnode) {
            if (OBF16) {
                u32x2 po;
                po.x = (uint)bf16_rne(o.x) | ((uint)bf16_rne(o.y) << 16);
                po.y = (uint)bf16_rne(o.z) | ((uint)bf16_rne(o.w) << 16);
                __builtin_nontemporal_store(
                    po, (u32x2*)out + (size_t)node * 32 + hl);
            } else {
                __builtin_nontemporal_store(
                    o, (f32x4*)out + (size_t)node * 32 + hl);
            }
        }
    }
}

// ---------------------------------------------------------------------------
extern "C" void kernel_launch(void* const* d_in, const int* in_sizes, int n_in,
                              void* d_out, int out_size, void* d_ws, size_t ws_size,
                              hipStream_t stream) {
    const float* x   = (const float*)d_in[0];
    const int*   ei  = (const int*)d_in[1];
    const float* Wl0 = (const float*)d_in[2];
    const float* Wr0 = (const float*)d_in[3];
    const float* at0 = (const float*)d_in[4];
    const float* b0  = (const float*)d_in[5];
    const float* g0  = (const float*)d_in[6];
    const float* be0 = (const float*)d_in[7];
    const float* Wl1 = (const float*)d_in[8];
    const float* Wr1 = (const float*)d_in[9];
    const float* at1 = (const float*)d_in[10];
    const float* b1  = (const float*)d_in[11];
    const float* g1  = (const float*)d_in[12];
    const float* be1 = (const float*)d_in[13];

    const int NF = in_sizes[0];        // N*128
    const int n  = NF / 128;           // nodes
    const int er = in_sizes[1] / 2;    // raw edges
    const int etot = er + n;           // + self-loops
    const int nb = (n + 1023) / 1024;  // scan blocks

    uint* A     = (uint*)d_ws;         // xl bf16-packed (N*64 uints)
    uint* B     = A + (size_t)NF / 2;  // xr bf16-packed
    uint* C1    = B + (size_t)NF / 2;  // layer-1 output, bf16-packed
    ushort* Whi = (ushort*)(C1 + (size_t)NF / 2);  // [2][32768] bf16 hi
    ushort* Wlo = Whi + 65536;                     // [2][32768] bf16 lo
    int* deg    = (int*)(Wlo + 65536);
    int* woff   = deg + n;
    int* offs   = woff + n;
    int* escan  = offs + (n + 4);      // n+1 used; +4 keeps colv 16B-aligned
    int* bsum   = escan + n;
    int* bpre   = bsum + 1024;
    int* colv   = bpre + 1024;
    float* C    = (float*)d_out;       // final fp32 output

    // ---- CSR build (XCD-partitioned) + both W conversions ----
    (void)hipMemsetAsync(deg, 0, (size_t)n * sizeof(int), stream);
    hist_part<<<2048, 256, 0, stream>>>(ei, er, etot, n, deg);
    scanA<<<nb, 1024, 0, stream>>>(deg, escan, bsum, n);
    scanB<<<1, 1024, 0, stream>>>(bsum, bpre, nb, offs, n);
    scanC<<<(n + 255) / 256, 256, 0, stream>>>(escan, bpre, offs, woff, n);
    fill_part<<<2048, 256, 0, stream>>>(ei, er, etot, n, woff, colv);
    cvt_w2<<<256, 256, 0, stream>>>(Wl0, Wr0, Wl1, Wr1, Whi, Wlo);

    const int gblk = (n + 63) / 64;

    // ---- layer 1: fp32 x -> A,B ; agg -> C1 (bf16 packed), resid = x fp32 ----
    gemm_mfma<false><<<gblk, 256, 0, stream>>>(x, Whi, Wlo, A, B, n);
    gat_agg<false, true><<<2048, 256, 0, stream>>>(
        A, B, offs, colv, at0, b0, g0, be0, x, C1, n);
    // ---- layer 2: bf16 C1 -> A,B ; agg -> d_out fp32, resid = C1 bf16 ----
    gemm_mfma<true><<<gblk, 256, 0, stream>>>(C1, Whi + 32768, Wlo + 32768,
                                              A, B, n);
    gat_agg<true, false><<<2048, 256, 0, stream>>>(
        A, B, offs, colv, at1, b1, g1, be1, C1, C, n);
}

// Round 16
// 458.542 us; speedup vs baseline: 1.0481x; 1.0481x over previous
//
#include <hip/hip_runtime.h>
#include <cstdint>

#define LEAKY 0.2f
#define LN_EPS 1e-5f

typedef __attribute__((ext_vector_type(8))) short short8;   // 8 x bf16 (4 VGPR)
typedef __attribute__((ext_vector_type(4))) float f32x4;    // MFMA accum
typedef __attribute__((ext_vector_type(2))) float f32x2;

__device__ __forceinline__ ushort bf16_rne(float x) {
    unsigned u = __float_as_uint(x);
    unsigned r = (u + 0x7fffu + ((u >> 16) & 1u)) >> 16;
    return (ushort)r;
}
__device__ __forceinline__ float bf16_to_f(ushort h) {
    return __uint_as_float(((unsigned)h) << 16);
}
__device__ __forceinline__ f32x2 unpk(uint u) {
    f32x2 r;
    r.x = __uint_as_float(u << 16);
    r.y = __uint_as_float(u & 0xffff0000u);
    return r;
}
__device__ __forceinline__ uint cvt_pk_bf16(float lo, float hi) {
    uint r;
    asm("v_cvt_pk_bf16_f32 %0, %1, %2" : "=v"(r) : "v"(lo), "v"(hi));
    return r;
}

// ---------------------------------------------------------------------------
// CSR build, XCD-partitioned (round-12 win: no cross-XCD cacheline ping-pong)
// ---------------------------------------------------------------------------
__global__ void hist_part(const int* __restrict__ ei, int er, int etot, int n,
                          int* __restrict__ deg) {
    const int xcd = blockIdx.x & 7;
    const int lo = (int)((long long)n * xcd >> 3);
    const int hi = (int)((long long)n * (xcd + 1) >> 3);
    const int stride = (gridDim.x >> 3) * blockDim.x;
    for (int e = (blockIdx.x >> 3) * blockDim.x + threadIdx.x; e < etot;
         e += stride) {
        int dst = (e < er) ? ei[er + e] : (e - er);
        if (dst >= lo && dst < hi) atomicAdd(&deg[dst], 1);
    }
}

__global__ void fill_part(const int* __restrict__ ei, int er, int etot, int n,
                          int* __restrict__ woff, int* __restrict__ colv) {
    const int xcd = blockIdx.x & 7;
    const int lo = (int)((long long)n * xcd >> 3);
    const int hi = (int)((long long)n * (xcd + 1) >> 3);
    const int stride = (gridDim.x >> 3) * blockDim.x;
    for (int e = (blockIdx.x >> 3) * blockDim.x + threadIdx.x; e < etot;
         e += stride) {
        int dst = (e < er) ? ei[er + e] : (e - er);
        if (dst >= lo && dst < hi) {
            int src = (e < er) ? ei[e] : dst;
            int pos = atomicAdd(&woff[dst], 1);
            colv[pos] = src;
        }
    }
}

__global__ __launch_bounds__(1024) void scanA(const int* __restrict__ deg,
                                              int* __restrict__ escan,
                                              int* __restrict__ bsum, int n) {
    __shared__ int wsum[16], wpre[16];
    const int lane = threadIdx.x & 63, wv = threadIdx.x >> 6;
    const int i = blockIdx.x * 1024 + threadIdx.x;
    int v = (i < n) ? deg[i] : 0;
    int x = v;
#pragma unroll
    for (int off = 1; off < 64; off <<= 1) {
        int y = __shfl_up(x, off, 64);
        if (lane >= off) x += y;
    }
    if (lane == 63) wsum[wv] = x;
    __syncthreads();
    if (wv == 0) {
        int s = (lane < 16) ? wsum[lane] : 0;
#pragma unroll
        for (int off = 1; off < 16; off <<= 1) {
            int y = __shfl_up(s, off, 64);
            if (lane >= off) s += y;
        }
        if (lane < 16) wpre[lane] = s;
    }
    __syncthreads();
    int excl = x - v + (wv ? wpre[wv - 1] : 0);
    if (i < n) escan[i] = excl;
    if (threadIdx.x == 1023) bsum[blockIdx.x] = wpre[15];
}

__global__ __launch_bounds__(1024) void scanB(const int* __restrict__ bsum,
                                              int* __restrict__ bpre, int nb,
                                              int* __restrict__ offs, int n) {
    __shared__ int wsum[16], wpre[16];
    const int lane = threadIdx.x & 63, wv = threadIdx.x >> 6;
    const int i = threadIdx.x;
    int v = (i < nb) ? bsum[i] : 0;
    int x = v;
#pragma unroll
    for (int off = 1; off < 64; off <<= 1) {
        int y = __shfl_up(x, off, 64);
        if (lane >= off) x += y;
    }
    if (lane == 63) wsum[wv] = x;
    __syncthreads();
    if (wv == 0) {
        int s = (lane < 16) ? wsum[lane] : 0;
#pragma unroll
        for (int off = 1; off < 16; off <<= 1) {
            int y = __shfl_up(s, off, 64);
            if (lane >= off) s += y;
        }
        if (lane < 16) wpre[lane] = s;
    }
    __syncthreads();
    if (i < nb) bpre[i] = x - v + (wv ? wpre[wv - 1] : 0);
    if (threadIdx.x == 1023) offs[n] = wpre[15];
}

__global__ void scanC(const int* __restrict__ escan, const int* __restrict__ bpre,
                      int* __restrict__ offs, int* __restrict__ woff, int n) {
    int i = blockIdx.x * 256 + threadIdx.x;
    if (i >= n) return;
    int o = escan[i] + bpre[i >> 10];
    offs[i] = o;
    woff[i] = o;
}

// ---------------------------------------------------------------------------
// Both layers' W -> per-MFMA-fragment bf16 hi/lo layout (one dispatch).
// ---------------------------------------------------------------------------
__global__ void cvt_w2(const float* __restrict__ Wl0, const float* __restrict__ Wr0,
                       const float* __restrict__ Wl1, const float* __restrict__ Wr1,
                       ushort* __restrict__ Whi, ushort* __restrict__ Wlo) {
    int t = blockIdx.x * 256 + threadIdx.x;     // 0..65535
    int layer = t >> 15;
    int i = t & 32767;
    int colblk = i >> 11;
    int ks = (i >> 9) & 3;
    int lane = (i >> 3) & 63;
    int j = i & 7;
    int col = colblk * 16 + (lane & 15);
    int k = ks * 32 + (lane >> 4) * 8 + j;
    const float* Wl = layer ? Wl1 : Wl0;
    const float* Wr = layer ? Wr1 : Wr0;
    float v = (col < 128) ? Wl[(size_t)k * 128 + col]
                          : Wr[(size_t)k * 128 + (col - 128)];
    ushort h = bf16_rne(v);
    Whi[t] = h;
    Wlo[t] = bf16_rne(v - bf16_to_f(h));
}

// ---------------------------------------------------------------------------
// Dual GEMM, 2 MFMA per fragment: A = rne-bf16 (fp32 path converts via
// v_cvt_pk_bf16_f32, 1 op / 2 elems; A-lo term dropped — error ~2e-3,
// below the bf16-storage rounding already accepted). W keeps hi/lo split.
// Output packed bf16 pairs via shfl_xor lane-pairing.
// ---------------------------------------------------------------------------
template <bool ABF16>
__global__ __launch_bounds__(256) void gemm_mfma(
    const void* __restrict__ Xin,
    const ushort* __restrict__ Wfhi, const ushort* __restrict__ Wflo,
    uint* __restrict__ Olb, uint* __restrict__ Orb, int nrows) {
    __shared__ float4 xs[64 * 32];              // 32 KiB (fp32) / 16 KiB used (bf16)
    const int t = threadIdx.x;
    const int wave = t >> 6, lane = t & 63;
    const int m0 = blockIdx.x * 64;
    if (ABF16) {
        const uint4* Xv = (const uint4*)Xin + (size_t)m0 * 16;
        uint4* xsb = (uint4*)xs;
#pragma unroll
        for (int i = 0; i < 4; ++i) {
            int idx = i * 256 + t;
            int row = idx >> 4, kc = idx & 15;
            uint4 v = {0u, 0u, 0u, 0u};
            if (m0 + row < nrows) v = Xv[idx];
            xsb[row * 16 + (kc ^ (row & 7))] = v;
        }
    } else {
        const float4* Xv = (const float4*)Xin + (size_t)m0 * 32;
#pragma unroll
        for (int i = 0; i < 8; ++i) {
            int idx = i * 256 + t;
            int row = idx >> 5, kc = idx & 31;
            float4 v = {0.f, 0.f, 0.f, 0.f};
            if (m0 + row < nrows) v = Xv[idx];
            xs[row * 32 + (kc ^ (row & 7))] = v;
        }
    }
    __syncthreads();

    const int lrow = lane & 15;
    const int lkc = (lane >> 4) * 2;
    f32x4 acc[4][4];
#pragma unroll
    for (int mt = 0; mt < 4; ++mt)
#pragma unroll
        for (int nt = 0; nt < 4; ++nt) acc[mt][nt] = (f32x4){0.f, 0.f, 0.f, 0.f};

#pragma unroll 1
    for (int ks = 0; ks < 4; ++ks) {
        short8 ahi[4];
#pragma unroll
        for (int mt = 0; mt < 4; ++mt) {
            const int row = mt * 16 + lrow;
            if (ABF16) {
                const int slot = ks * 4 + (lane >> 4);
                uint4 w = ((const uint4*)xs)[row * 16 + (slot ^ (row & 7))];
                ahi[mt] = *(const short8*)&w;
            } else {
                const int kc0 = ks * 8 + lkc;
                float4 v0 = xs[row * 32 + (kc0 ^ (row & 7))];
                float4 v1 = xs[row * 32 + ((kc0 + 1) ^ (row & 7))];
                uint4 q;
                q.x = cvt_pk_bf16(v0.x, v0.y);
                q.y = cvt_pk_bf16(v0.z, v0.w);
                q.z = cvt_pk_bf16(v1.x, v1.y);
                q.w = cvt_pk_bf16(v1.z, v1.w);
                ahi[mt] = *(const short8*)&q;
            }
        }
#pragma unroll
        for (int nt = 0; nt < 4; ++nt) {
            size_t off = (((size_t)(wave * 4 + nt) * 4 + ks) * 64 + lane) * 8;
            short8 bhi = *(const short8*)&Wfhi[off];
            short8 blo = *(const short8*)&Wflo[off];
#pragma unroll
            for (int mt = 0; mt < 4; ++mt) {
                acc[mt][nt] = __builtin_amdgcn_mfma_f32_16x16x32_bf16(
                    ahi[mt], blo, acc[mt][nt], 0, 0, 0);
                acc[mt][nt] = __builtin_amdgcn_mfma_f32_16x16x32_bf16(
                    ahi[mt], bhi, acc[mt][nt], 0, 0, 0);
            }
        }
    }
    // Epilogue: C/D frag col=lane&15, row=(lane>>4)*4+i; shfl_xor(1) pairs cols.
    uint* __restrict__ O = (wave < 2) ? Olb : Orb;
    const int cbase = (wave * 64) & 127;
    const int crow0 = (lane >> 4) * 4;
    const bool evn = (lane & 1) == 0;
#pragma unroll
    for (int mt = 0; mt < 4; ++mt) {
#pragma unroll
        for (int i = 0; i < 4; ++i) {
            const int row = m0 + mt * 16 + crow0 + i;
#pragma unroll
            for (int nt = 0; nt < 4; ++nt) {
                float val = acc[mt][nt][i];
                float pv = __shfl_xor(val, 1);
                uint pk = (uint)bf16_rne(val) | ((uint)bf16_rne(pv) << 16);
                if (evn && row < nrows) {
                    const int col = cbase + nt * 16 + lrow;
                    O[(size_t)row * 64 + (col >> 1)] = pk;
                }
            }
        }
    }
}

// ---------------------------------------------------------------------------
// Fused GATv2 agg + bias + ELU + residual + LayerNorm. One wave per node.
// (Round-13 version — round-14's 2-node split halved occupancy, reverted.)
// Wave-uniform CSR indices forced to SGPRs (readfirstlane) -> colv via scalar
// pipe, gathers in saddr form; pairwise math as f32x2 (v_pk_* ops).
// ---------------------------------------------------------------------------
template <bool RBF16, bool OBF16>
__global__ __launch_bounds__(256) void gat_agg(
    const uint* __restrict__ xl, const uint* __restrict__ xr,
    const int* __restrict__ offs, const int* __restrict__ colv,
    const float* __restrict__ att,
    const float* __restrict__ bias, const float* __restrict__ gamma,
    const float* __restrict__ beta, const void* __restrict__ resid,
    void* __restrict__ out, int nnode) {
    const int lane = threadIdx.x & 63;
    const int wid = __builtin_amdgcn_readfirstlane(threadIdx.x >> 6);
    const int wave0 = blockIdx.x * 4 + wid;
    const int wstride = gridDim.x * 4;
    const f32x2 att2 = ((const f32x2*)att)[lane];
    const f32x2 b2 = ((const f32x2*)bias)[lane];
    const f32x2 g2 = ((const f32x2*)gamma)[lane];
    const f32x2 be2 = ((const f32x2*)beta)[lane];
    for (int gid = wave0; gid < nnode; gid += wstride) {
        const uint xru = __builtin_nontemporal_load(xr + (size_t)gid * 64 + lane);
        const f32x2 xr2 = unpk(xru);
        float den = 0.f;
        f32x2 acc = {0.f, 0.f};
        int e = offs[gid];
        const int e1 = offs[gid + 1];
        for (; e + 4 <= e1; e += 4) {
            int s0 = __builtin_amdgcn_readfirstlane(colv[e]);
            int s1 = __builtin_amdgcn_readfirstlane(colv[e + 1]);
            int s2 = __builtin_amdgcn_readfirstlane(colv[e + 2]);
            int s3 = __builtin_amdgcn_readfirstlane(colv[e + 3]);
            uint u0 = xl[(size_t)s0 * 64 + lane];
            uint u1 = xl[(size_t)s1 * 64 + lane];
            uint u2 = xl[(size_t)s2 * 64 + lane];
            uint u3 = xl[(size_t)s3 * 64 + lane];
            f32x2 a0 = unpk(u0), a1 = unpk(u1), a2 = unpk(u2), a3 = unpk(u3);
            f32x2 m0 = a0 + xr2, m1 = a1 + xr2, m2 = a2 + xr2, m3 = a3 + xr2;
            f32x2 l0 = m0 * LEAKY, l1 = m1 * LEAKY, l2 = m2 * LEAKY, l3 = m3 * LEAKY;
            m0.x = fmaxf(m0.x, l0.x); m0.y = fmaxf(m0.y, l0.y);
            m1.x = fmaxf(m1.x, l1.x); m1.y = fmaxf(m1.y, l1.y);
            m2.x = fmaxf(m2.x, l2.x); m2.y = fmaxf(m2.y, l2.y);
            m3.x = fmaxf(m3.x, l3.x); m3.y = fmaxf(m3.y, l3.y);
            f32x2 t0 = m0 * att2, t1 = m1 * att2, t2 = m2 * att2, t3 = m3 * att2;
            float p0 = t0.x + t0.y, p1 = t1.x + t1.y;
            float p2 = t2.x + t2.y, p3 = t3.x + t3.y;
            p0 += __shfl_xor(p0, 1); p0 += __shfl_xor(p0, 2); p0 += __shfl_xor(p0, 4);
            p1 += __shfl_xor(p1, 1); p1 += __shfl_xor(p1, 2); p1 += __shfl_xor(p1, 4);
            p2 += __shfl_xor(p2, 1); p2 += __shfl_xor(p2, 2); p2 += __shfl_xor(p2, 4);
            p3 += __shfl_xor(p3, 1); p3 += __shfl_xor(p3, 2); p3 += __shfl_xor(p3, 4);
            float ex0 = __expf(p0), ex1 = __expf(p1);
            float ex2 = __expf(p2), ex3 = __expf(p3);
            den += (ex0 + ex1) + (ex2 + ex3);
            acc += a0 * ex0;
            acc += a1 * ex1;
            acc += a2 * ex2;
            acc += a3 * ex3;
        }
        for (; e < e1; ++e) {
            int s0 = __builtin_amdgcn_readfirstlane(colv[e]);
            uint u0 = xl[(size_t)s0 * 64 + lane];
            f32x2 a0 = unpk(u0);
            f32x2 m0 = a0 + xr2;
            f32x2 l0 = m0 * LEAKY;
            m0.x = fmaxf(m0.x, l0.x); m0.y = fmaxf(m0.y, l0.y);
            f32x2 t0 = m0 * att2;
            float p0 = t0.x + t0.y;
            p0 += __shfl_xor(p0, 1); p0 += __shfl_xor(p0, 2); p0 += __shfl_xor(p0, 4);
            float ex0 = __expf(p0);
            den += ex0;
            acc += a0 * ex0;
        }
        const float inv_den = 1.f / den;
        f32x2 v = acc * inv_den + b2;
        v.x = v.x > 0.f ? v.x : expm1f(v.x);     // ELU (alpha=1)
        v.y = v.y > 0.f ? v.y : expm1f(v.y);
        f32x2 r2;
        if (RBF16) {
            uint ru = __builtin_nontemporal_load(
                (const uint*)resid + (size_t)gid * 64 + lane);
            r2 = unpk(ru);
        } else {
            r2 = __builtin_nontemporal_load(
                (const f32x2*)resid + (size_t)gid * 64 + lane);
        }
        f32x2 tv = v + r2;
        float s = tv.x + tv.y, ss = tv.x * tv.x + tv.y * tv.y;
#pragma unroll
        for (int m = 1; m < 64; m <<= 1) {
            s += __shfl_xor(s, m);
            ss += __shfl_xor(ss, m);
        }
        const float mu = s * 0.0078125f;
        const float var = ss * 0.0078125f - mu * mu;
        const float iv = rsqrtf(var + LN_EPS);
        f32x2 o = (tv - mu) * iv * g2 + be2;
        if (OBF16) {
            uint po = (uint)bf16_rne(o.x) | ((uint)bf16_rne(o.y) << 16);
            __builtin_nontemporal_store(po, (uint*)out + (size_t)gid * 64 + lane);
        } else {
            __builtin_nontemporal_store(o, (f32x2*)out + (size_t)gid * 64 + lane);
        }
    }
}

// ---------------------------------------------------------------------------
extern "C" void kernel_launch(void* const* d_in, const int* in_sizes, int n_in,
                              void* d_out, int out_size, void* d_ws, size_t ws_size,
                              hipStream_t stream) {
    const float* x   = (const float*)d_in[0];
    const int*   ei  = (const int*)d_in[1];
    const float* Wl0 = (const float*)d_in[2];
    const float* Wr0 = (const float*)d_in[3];
    const float* at0 = (const float*)d_in[4];
    const float* b0  = (const float*)d_in[5];
    const float* g0  = (const float*)d_in[6];
    const float* be0 = (const float*)d_in[7];
    const float* Wl1 = (const float*)d_in[8];
    const float* Wr1 = (const float*)d_in[9];
    const float* at1 = (const float*)d_in[10];
    const float* b1  = (const float*)d_in[11];
    const float* g1  = (const float*)d_in[12];
    const float* be1 = (const float*)d_in[13];

    const int NF = in_sizes[0];        // N*128
    const int n  = NF / 128;           // nodes
    const int er = in_sizes[1] / 2;    // raw edges
    const int etot = er + n;           // + self-loops
    const int nb = (n + 1023) / 1024;  // scan blocks

    uint* A     = (uint*)d_ws;         // xl bf16-packed (N*64 uints)
    uint* B     = A + (size_t)NF / 2;  // xr bf16-packed
    uint* C1    = B + (size_t)NF / 2;  // layer-1 output, bf16-packed
    ushort* Whi = (ushort*)(C1 + (size_t)NF / 2);  // [2][32768] bf16 hi
    ushort* Wlo = Whi + 65536;                     // [2][32768] bf16 lo
    int* deg    = (int*)(Wlo + 65536);
    int* woff   = deg + n;
    int* offs   = woff + n;
    int* escan  = offs + (n + 4);      // n+1 used; +4 keeps colv 16B-aligned
    int* bsum   = escan + n;
    int* bpre   = bsum + 1024;
    int* colv   = bpre + 1024;
    float* C    = (float*)d_out;       // final fp32 output

    // ---- CSR build (XCD-partitioned) + both W conversions ----
    (void)hipMemsetAsync(deg, 0, (size_t)n * sizeof(int), stream);
    hist_part<<<2048, 256, 0, stream>>>(ei, er, etot, n, deg);
    scanA<<<nb, 1024, 0, stream>>>(deg, escan, bsum, n);
    scanB<<<1, 1024, 0, stream>>>(bsum, bpre, nb, offs, n);
    scanC<<<(n + 255) / 256, 256, 0, stream>>>(escan, bpre, offs, woff, n);
    fill_part<<<2048, 256, 0, stream>>>(ei, er, etot, n, woff, colv);
    cvt_w2<<<256, 256, 0, stream>>>(Wl0, Wr0, Wl1, Wr1, Whi, Wlo);

    const int gblk = (n + 63) / 64;

    // ---- layer 1: fp32 x -> A,B ; agg -> C1 (bf16 packed), resid = x fp32 ----
    gemm_mfma<false><<<gblk, 256, 0, stream>>>(x, Whi, Wlo, A, B, n);
    gat_agg<false, true><<<2048, 256, 0, stream>>>(
        A, B, offs, colv, at0, b0, g0, be0, x, C1, n);
    // ---- layer 2: bf16 C1 -> A,B ; agg -> d_out fp32, resid = C1 bf16 ----
    gemm_mfma<true><<<gblk, 256, 0, stream>>>(C1, Whi + 32768, Wlo + 32768,
                                              A, B, n);
    gat_agg<true, false><<<2048, 256, 0, stream>>>(
        A, B, offs, colv, at1, b1, g1, be1, C1, C, n);
}

// Round 18
// 457.885 us; speedup vs baseline: 1.0496x; 1.0014x over previous
//
#include <hip/hip_runtime.h>
#include <cstdint>

#define LEAKY 0.2f
#define LN_EPS 1e-5f

typedef __attribute__((ext_vector_type(8))) short short8;   // 8 x bf16 (4 VGPR)
typedef __attribute__((ext_vector_type(4))) float f32x4;    // MFMA accum
typedef __attribute__((ext_vector_type(2))) float f32x2;

__device__ __forceinline__ ushort bf16_rne(float x) {
    unsigned u = __float_as_uint(x);
    unsigned r = (u + 0x7fffu + ((u >> 16) & 1u)) >> 16;
    return (ushort)r;
}
__device__ __forceinline__ float bf16_to_f(ushort h) {
    return __uint_as_float(((unsigned)h) << 16);
}
__device__ __forceinline__ f32x2 unpk(uint u) {
    f32x2 r;
    r.x = __uint_as_float(u << 16);
    r.y = __uint_as_float(u & 0xffff0000u);
    return r;
}
__device__ __forceinline__ uint cvt_pk_bf16(float lo, float hi) {
    uint r;
    asm("v_cvt_pk_bf16_f32 %0, %1, %2" : "=v"(r) : "v"(lo), "v"(hi));
    return r;
}

// ---------------------------------------------------------------------------
// CSR build, XCD-partitioned (round-12 win: no cross-XCD cacheline ping-pong)
// ---------------------------------------------------------------------------
__global__ void hist_part(const int* __restrict__ ei, int er, int etot, int n,
                          int* __restrict__ deg) {
    const int xcd = blockIdx.x & 7;
    const int lo = (int)((long long)n * xcd >> 3);
    const int hi = (int)((long long)n * (xcd + 1) >> 3);
    const int stride = (gridDim.x >> 3) * blockDim.x;
    for (int e = (blockIdx.x >> 3) * blockDim.x + threadIdx.x; e < etot;
         e += stride) {
        int dst = (e < er) ? ei[er + e] : (e - er);
        if (dst >= lo && dst < hi) atomicAdd(&deg[dst], 1);
    }
}

__global__ void fill_part(const int* __restrict__ ei, int er, int etot, int n,
                          int* __restrict__ woff, int* __restrict__ colv) {
    const int xcd = blockIdx.x & 7;
    const int lo = (int)((long long)n * xcd >> 3);
    const int hi = (int)((long long)n * (xcd + 1) >> 3);
    const int stride = (gridDim.x >> 3) * blockDim.x;
    for (int e = (blockIdx.x >> 3) * blockDim.x + threadIdx.x; e < etot;
         e += stride) {
        int dst = (e < er) ? ei[er + e] : (e - er);
        if (dst >= lo && dst < hi) {
            int src = (e < er) ? ei[e] : dst;
            int pos = atomicAdd(&woff[dst], 1);
            colv[pos] = src;
        }
    }
}

__global__ __launch_bounds__(1024) void scanA(const int* __restrict__ deg,
                                              int* __restrict__ escan,
                                              int* __restrict__ bsum, int n) {
    __shared__ int wsum[16], wpre[16];
    const int lane = threadIdx.x & 63, wv = threadIdx.x >> 6;
    const int i = blockIdx.x * 1024 + threadIdx.x;
    int v = (i < n) ? deg[i] : 0;
    int x = v;
#pragma unroll
    for (int off = 1; off < 64; off <<= 1) {
        int y = __shfl_up(x, off, 64);
        if (lane >= off) x += y;
    }
    if (lane == 63) wsum[wv] = x;
    __syncthreads();
    if (wv == 0) {
        int s = (lane < 16) ? wsum[lane] : 0;
#pragma unroll
        for (int off = 1; off < 16; off <<= 1) {
            int y = __shfl_up(s, off, 64);
            if (lane >= off) s += y;
        }
        if (lane < 16) wpre[lane] = s;
    }
    __syncthreads();
    int excl = x - v + (wv ? wpre[wv - 1] : 0);
    if (i < n) escan[i] = excl;
    if (threadIdx.x == 1023) bsum[blockIdx.x] = wpre[15];
}

__global__ __launch_bounds__(1024) void scanB(const int* __restrict__ bsum,
                                              int* __restrict__ bpre, int nb,
                                              int* __restrict__ offs, int n) {
    __shared__ int wsum[16], wpre[16];
    const int lane = threadIdx.x & 63, wv = threadIdx.x >> 6;
    const int i = threadIdx.x;
    int v = (i < nb) ? bsum[i] : 0;
    int x = v;
#pragma unroll
    for (int off = 1; off < 64; off <<= 1) {
        int y = __shfl_up(x, off, 64);
        if (lane >= off) x += y;
    }
    if (lane == 63) wsum[wv] = x;
    __syncthreads();
    if (wv == 0) {
        int s = (lane < 16) ? wsum[lane] : 0;
#pragma unroll
        for (int off = 1; off < 16; off <<= 1) {
            int y = __shfl_up(s, off, 64);
            if (lane >= off) s += y;
        }
        if (lane < 16) wpre[lane] = s;
    }
    __syncthreads();
    if (i < nb) bpre[i] = x - v + (wv ? wpre[wv - 1] : 0);
    if (threadIdx.x == 1023) offs[n] = wpre[15];
}

__global__ void scanC(const int* __restrict__ escan, const int* __restrict__ bpre,
                      int* __restrict__ offs, int* __restrict__ woff, int n) {
    int i = blockIdx.x * 256 + threadIdx.x;
    if (i >= n) return;
    int o = escan[i] + bpre[i >> 10];
    offs[i] = o;
    woff[i] = o;
}

// ---------------------------------------------------------------------------
// Both layers' W -> per-MFMA-fragment bf16 hi/lo layout (one dispatch).
// ---------------------------------------------------------------------------
__global__ void cvt_w2(const float* __restrict__ Wl0, const float* __restrict__ Wr0,
                       const float* __restrict__ Wl1, const float* __restrict__ Wr1,
                       ushort* __restrict__ Whi, ushort* __restrict__ Wlo) {
    int t = blockIdx.x * 256 + threadIdx.x;     // 0..65535
    int layer = t >> 15;
    int i = t & 32767;
    int colblk = i >> 11;
    int ks = (i >> 9) & 3;
    int lane = (i >> 3) & 63;
    int j = i & 7;
    int col = colblk * 16 + (lane & 15);
    int k = ks * 32 + (lane >> 4) * 8 + j;
    const float* Wl = layer ? Wl1 : Wl0;
    const float* Wr = layer ? Wr1 : Wr0;
    float v = (col < 128) ? Wl[(size_t)k * 128 + col]
                          : Wr[(size_t)k * 128 + (col - 128)];
    ushort h = bf16_rne(v);
    Whi[t] = h;
    Wlo[t] = bf16_rne(v - bf16_to_f(h));
}

// ---------------------------------------------------------------------------
// Dual GEMM, 2 MFMA per fragment — UNCHANGED from round 16 (clean A/B:
// gat_agg speedup should expose this kernel in next round's top-5).
// ---------------------------------------------------------------------------
template <bool ABF16>
__global__ __launch_bounds__(256) void gemm_mfma(
    const void* __restrict__ Xin,
    const ushort* __restrict__ Wfhi, const ushort* __restrict__ Wflo,
    uint* __restrict__ Olb, uint* __restrict__ Orb, int nrows) {
    __shared__ float4 xs[64 * 32];              // 32 KiB (fp32) / 16 KiB used (bf16)
    const int t = threadIdx.x;
    const int wave = t >> 6, lane = t & 63;
    const int m0 = blockIdx.x * 64;
    if (ABF16) {
        const uint4* Xv = (const uint4*)Xin + (size_t)m0 * 16;
        uint4* xsb = (uint4*)xs;
#pragma unroll
        for (int i = 0; i < 4; ++i) {
            int idx = i * 256 + t;
            int row = idx >> 4, kc = idx & 15;
            uint4 v = {0u, 0u, 0u, 0u};
            if (m0 + row < nrows) v = Xv[idx];
            xsb[row * 16 + (kc ^ (row & 7))] = v;
        }
    } else {
        const float4* Xv = (const float4*)Xin + (size_t)m0 * 32;
#pragma unroll
        for (int i = 0; i < 8; ++i) {
            int idx = i * 256 + t;
            int row = idx >> 5, kc = idx & 31;
            float4 v = {0.f, 0.f, 0.f, 0.f};
            if (m0 + row < nrows) v = Xv[idx];
            xs[row * 32 + (kc ^ (row & 7))] = v;
        }
    }
    __syncthreads();

    const int lrow = lane & 15;
    const int lkc = (lane >> 4) * 2;
    f32x4 acc[4][4];
#pragma unroll
    for (int mt = 0; mt < 4; ++mt)
#pragma unroll
        for (int nt = 0; nt < 4; ++nt) acc[mt][nt] = (f32x4){0.f, 0.f, 0.f, 0.f};

#pragma unroll 1
    for (int ks = 0; ks < 4; ++ks) {
        short8 ahi[4];
#pragma unroll
        for (int mt = 0; mt < 4; ++mt) {
            const int row = mt * 16 + lrow;
            if (ABF16) {
                const int slot = ks * 4 + (lane >> 4);
                uint4 w = ((const uint4*)xs)[row * 16 + (slot ^ (row & 7))];
                ahi[mt] = *(const short8*)&w;
            } else {
                const int kc0 = ks * 8 + lkc;
                float4 v0 = xs[row * 32 + (kc0 ^ (row & 7))];
                float4 v1 = xs[row * 32 + ((kc0 + 1) ^ (row & 7))];
                uint4 q;
                q.x = cvt_pk_bf16(v0.x, v0.y);
                q.y = cvt_pk_bf16(v0.z, v0.w);
                q.z = cvt_pk_bf16(v1.x, v1.y);
                q.w = cvt_pk_bf16(v1.z, v1.w);
                ahi[mt] = *(const short8*)&q;
            }
        }
#pragma unroll
        for (int nt = 0; nt < 4; ++nt) {
            size_t off = (((size_t)(wave * 4 + nt) * 4 + ks) * 64 + lane) * 8;
            short8 bhi = *(const short8*)&Wfhi[off];
            short8 blo = *(const short8*)&Wflo[off];
#pragma unroll
            for (int mt = 0; mt < 4; ++mt) {
                acc[mt][nt] = __builtin_amdgcn_mfma_f32_16x16x32_bf16(
                    ahi[mt], blo, acc[mt][nt], 0, 0, 0);
                acc[mt][nt] = __builtin_amdgcn_mfma_f32_16x16x32_bf16(
                    ahi[mt], bhi, acc[mt][nt], 0, 0, 0);
            }
        }
    }
    // Epilogue: C/D frag col=lane&15, row=(lane>>4)*4+i; shfl_xor(1) pairs cols.
    uint* __restrict__ O = (wave < 2) ? Olb : Orb;
    const int cbase = (wave * 64) & 127;
    const int crow0 = (lane >> 4) * 4;
    const bool evn = (lane & 1) == 0;
#pragma unroll
    for (int mt = 0; mt < 4; ++mt) {
#pragma unroll
        for (int i = 0; i < 4; ++i) {
            const int row = m0 + mt * 16 + crow0 + i;
#pragma unroll
            for (int nt = 0; nt < 4; ++nt) {
                float val = acc[mt][nt][i];
                float pv = __shfl_xor(val, 1);
                uint pk = (uint)bf16_rne(val) | ((uint)bf16_rne(pv) << 16);
                if (evn && row < nrows) {
                    const int col = cbase + nt * 16 + lrow;
                    O[(size_t)row * 64 + (col >> 1)] = pk;
                }
            }
        }
    }
}

// ---------------------------------------------------------------------------
// Fused GATv2 agg + bias + ELU + residual + LayerNorm. One wave per node.
// 8-edge unroll (8 gathers in flight; loop overhead amortized). Wave-uniform
// CSR indices via readfirstlane -> scalar-pipe colv, saddr-form gathers.
// ---------------------------------------------------------------------------
template <bool RBF16, bool OBF16>
__global__ __launch_bounds__(256) void gat_agg(
    const uint* __restrict__ xl, const uint* __restrict__ xr,
    const int* __restrict__ offs, const int* __restrict__ colv,
    const float* __restrict__ att,
    const float* __restrict__ bias, const float* __restrict__ gamma,
    const float* __restrict__ beta, const void* __restrict__ resid,
    void* __restrict__ out, int nnode) {
    const int lane = threadIdx.x & 63;
    const int wid = __builtin_amdgcn_readfirstlane(threadIdx.x >> 6);
    const int wave0 = blockIdx.x * 4 + wid;
    const int wstride = gridDim.x * 4;
    const f32x2 att2 = ((const f32x2*)att)[lane];
    const f32x2 b2 = ((const f32x2*)bias)[lane];
    const f32x2 g2 = ((const f32x2*)gamma)[lane];
    const f32x2 be2 = ((const f32x2*)beta)[lane];
    for (int gid = wave0; gid < nnode; gid += wstride) {
        const uint xru = __builtin_nontemporal_load(xr + (size_t)gid * 64 + lane);
        const f32x2 xr2 = unpk(xru);
        float den = 0.f;
        f32x2 acc = {0.f, 0.f};
        int e = offs[gid];
        const int e1 = offs[gid + 1];
        for (; e + 8 <= e1; e += 8) {
            int s[8];
#pragma unroll
            for (int k = 0; k < 8; ++k)
                s[k] = __builtin_amdgcn_readfirstlane(colv[e + k]);
            uint u[8];
#pragma unroll
            for (int k = 0; k < 8; ++k) u[k] = xl[(size_t)s[k] * 64 + lane];
#pragma unroll
            for (int k = 0; k < 8; ++k) {
                f32x2 a = unpk(u[k]);
                f32x2 m = a + xr2;
                f32x2 l = m * LEAKY;
                m.x = fmaxf(m.x, l.x); m.y = fmaxf(m.y, l.y);
                f32x2 t = m * att2;
                float p = t.x + t.y;
                p += __shfl_xor(p, 1); p += __shfl_xor(p, 2); p += __shfl_xor(p, 4);
                float ex = __expf(p);
                den += ex;
                acc += a * ex;
            }
        }
        for (; e + 4 <= e1; e += 4) {
            int s[4];
#pragma unroll
            for (int k = 0; k < 4; ++k)
                s[k] = __builtin_amdgcn_readfirstlane(colv[e + k]);
            uint u[4];
#pragma unroll
            for (int k = 0; k < 4; ++k) u[k] = xl[(size_t)s[k] * 64 + lane];
#pragma unroll
            for (int k = 0; k < 4; ++k) {
                f32x2 a = unpk(u[k]);
                f32x2 m = a + xr2;
                f32x2 l = m * LEAKY;
                m.x = fmaxf(m.x, l.x); m.y = fmaxf(m.y, l.y);
                f32x2 t = m * att2;
                float p = t.x + t.y;
                p += __shfl_xor(p, 1); p += __shfl_xor(p, 2); p += __shfl_xor(p, 4);
                float ex = __expf(p);
                den += ex;
                acc += a * ex;
            }
        }
        for (; e < e1; ++e) {
            int s0 = __builtin_amdgcn_readfirstlane(colv[e]);
            uint u0 = xl[(size_t)s0 * 64 + lane];
            f32x2 a0 = unpk(u0);
            f32x2 m0 = a0 + xr2;
            f32x2 l0 = m0 * LEAKY;
            m0.x = fmaxf(m0.x, l0.x); m0.y = fmaxf(m0.y, l0.y);
            f32x2 t0 = m0 * att2;
            float p0 = t0.x + t0.y;
            p0 += __shfl_xor(p0, 1); p0 += __shfl_xor(p0, 2); p0 += __shfl_xor(p0, 4);
            float ex0 = __expf(p0);
            den += ex0;
            acc += a0 * ex0;
        }
        const float inv_den = 1.f / den;
        f32x2 v = acc * inv_den + b2;
        v.x = v.x > 0.f ? v.x : expm1f(v.x);     // ELU (alpha=1)
        v.y = v.y > 0.f ? v.y : expm1f(v.y);
        f32x2 r2;
        if (RBF16) {
            uint ru = __builtin_nontemporal_load(
                (const uint*)resid + (size_t)gid * 64 + lane);
            r2 = unpk(ru);
        } else {
            r2 = __builtin_nontemporal_load(
                (const f32x2*)resid + (size_t)gid * 64 + lane);
        }
        f32x2 tv = v + r2;
        float s = tv.x + tv.y, ss = tv.x * tv.x + tv.y * tv.y;
#pragma unroll
        for (int m = 1; m < 64; m <<= 1) {
            s += __shfl_xor(s, m);
            ss += __shfl_xor(ss, m);
        }
        const float mu = s * 0.0078125f;
        const float var = ss * 0.0078125f - mu * mu;
        const float iv = rsqrtf(var + LN_EPS);
        f32x2 o = (tv - mu) * iv * g2 + be2;
        if (OBF16) {
            uint po = (uint)bf16_rne(o.x) | ((uint)bf16_rne(o.y) << 16);
            __builtin_nontemporal_store(po, (uint*)out + (size_t)gid * 64 + lane);
        } else {
            __builtin_nontemporal_store(o, (f32x2*)out + (size_t)gid * 64 + lane);
        }
    }
}

// ---------------------------------------------------------------------------
extern "C" void kernel_launch(void* const* d_in, const int* in_sizes, int n_in,
                              void* d_out, int out_size, void* d_ws, size_t ws_size,
                              hipStream_t stream) {
    const float* x   = (const float*)d_in[0];
    const int*   ei  = (const int*)d_in[1];
    const float* Wl0 = (const float*)d_in[2];
    const float* Wr0 = (const float*)d_in[3];
    const float* at0 = (const float*)d_in[4];
    const float* b0  = (const float*)d_in[5];
    const float* g0  = (const float*)d_in[6];
    const float* be0 = (const float*)d_in[7];
    const float* Wl1 = (const float*)d_in[8];
    const float* Wr1 = (const float*)d_in[9];
    const float* at1 = (const float*)d_in[10];
    const float* b1  = (const float*)d_in[11];
    const float* g1  = (const float*)d_in[12];
    const float* be1 = (const float*)d_in[13];

    const int NF = in_sizes[0];        // N*128
    const int n  = NF / 128;           // nodes
    const int er = in_sizes[1] / 2;    // raw edges
    const int etot = er + n;           // + self-loops
    const int nb = (n + 1023) / 1024;  // scan blocks

    uint* A     = (uint*)d_ws;         // xl bf16-packed (N*64 uints)
    uint* B     = A + (size_t)NF / 2;  // xr bf16-packed
    uint* C1    = B + (size_t)NF / 2;  // layer-1 output, bf16-packed
    ushort* Whi = (ushort*)(C1 + (size_t)NF / 2);  // [2][32768] bf16 hi
    ushort* Wlo = Whi + 65536;                     // [2][32768] bf16 lo
    int* deg    = (int*)(Wlo + 65536);
    int* woff   = deg + n;
    int* offs   = woff + n;
    int* escan  = offs + (n + 4);      // n+1 used; +4 keeps colv 16B-aligned
    int* bsum   = escan + n;
    int* bpre   = bsum + 1024;
    int* colv   = bpre + 1024;
    float* C    = (float*)d_out;       // final fp32 output

    // ---- CSR build (XCD-partitioned) + both W conversions ----
    (void)hipMemsetAsync(deg, 0, (size_t)n * sizeof(int), stream);
    hist_part<<<2048, 256, 0, stream>>>(ei, er, etot, n, deg);
    scanA<<<nb, 1024, 0, stream>>>(deg, escan, bsum, n);
    scanB<<<1, 1024, 0, stream>>>(bsum, bpre, nb, offs, n);
    scanC<<<(n + 255) / 256, 256, 0, stream>>>(escan, bpre, offs, woff, n);
    fill_part<<<2048, 256, 0, stream>>>(ei, er, etot, n, woff, colv);
    cvt_w2<<<256, 256, 0, stream>>>(Wl0, Wr0, Wl1, Wr1, Whi, Wlo);

    const int gblk = (n + 63) / 64;

    // ---- layer 1: fp32 x -> A,B ; agg -> C1 (bf16 packed), resid = x fp32 ----
    gemm_mfma<false><<<gblk, 256, 0, stream>>>(x, Whi, Wlo, A, B, n);
    gat_agg<false, true><<<2048, 256, 0, stream>>>(
        A, B, offs, colv, at0, b0, g0, be0, x, C1, n);
    // ---- layer 2: bf16 C1 -> A,B ; agg -> d_out fp32, resid = C1 bf16 ----
    gemm_mfma<true><<<gblk, 256, 0, stream>>>(C1, Whi + 32768, Wlo + 32768,
                                              A, B, n);
    gat_agg<true, false><<<2048, 256, 0, stream>>>(
        A, B, offs, colv, at1, b1, g1, be1, C1, C, n);
}

// Round 19
// 448.496 us; speedup vs baseline: 1.0715x; 1.0209x over previous
//
#include <hip/hip_runtime.h>
#include <cstdint>

#define LEAKY 0.2f
#define LN_EPS 1e-5f

typedef __attribute__((ext_vector_type(8))) short short8;   // 8 x bf16 (4 VGPR)
typedef __attribute__((ext_vector_type(4))) float f32x4;    // MFMA accum
typedef __attribute__((ext_vector_type(2))) float f32x2;

__device__ __forceinline__ ushort bf16_rne(float x) {
    unsigned u = __float_as_uint(x);
    unsigned r = (u + 0x7fffu + ((u >> 16) & 1u)) >> 16;
    return (ushort)r;
}
__device__ __forceinline__ float bf16_to_f(ushort h) {
    return __uint_as_float(((unsigned)h) << 16);
}
__device__ __forceinline__ f32x2 unpk(uint u) {
    f32x2 r;
    r.x = __uint_as_float(u << 16);
    r.y = __uint_as_float(u & 0xffff0000u);
    return r;
}
__device__ __forceinline__ uint cvt_pk_bf16(float lo, float hi) {
    uint r;
    asm("v_cvt_pk_bf16_f32 %0, %1, %2" : "=v"(r) : "v"(lo), "v"(hi));
    return r;
}
// v + dpp_shuffle(v): single VALU op, no DS. CTRL: 0xB1 = quad_perm[1,0,3,2]
// (xor1), 0x4E = quad_perm[2,3,0,1] (xor2), 0x141 = row_half_mirror (== xor4
// once values are quad-uniform), 0x140 = row_mirror (== xor8 once 8-uniform).
template <int CTRL>
__device__ __forceinline__ float dpp_radd(float v) {
    int sh = __builtin_amdgcn_update_dpp(0, __float_as_int(v), CTRL, 0xF, 0xF, true);
    return v + __int_as_float(sh);
}

// ---------------------------------------------------------------------------
// CSR build, XCD-partitioned (round-12 win: no cross-XCD cacheline ping-pong)
// ---------------------------------------------------------------------------
__global__ void hist_part(const int* __restrict__ ei, int er, int etot, int n,
                          int* __restrict__ deg) {
    const int xcd = blockIdx.x & 7;
    const int lo = (int)((long long)n * xcd >> 3);
    const int hi = (int)((long long)n * (xcd + 1) >> 3);
    const int stride = (gridDim.x >> 3) * blockDim.x;
    for (int e = (blockIdx.x >> 3) * blockDim.x + threadIdx.x; e < etot;
         e += stride) {
        int dst = (e < er) ? ei[er + e] : (e - er);
        if (dst >= lo && dst < hi) atomicAdd(&deg[dst], 1);
    }
}

__global__ void fill_part(const int* __restrict__ ei, int er, int etot, int n,
                          int* __restrict__ woff, int* __restrict__ colv) {
    const int xcd = blockIdx.x & 7;
    const int lo = (int)((long long)n * xcd >> 3);
    const int hi = (int)((long long)n * (xcd + 1) >> 3);
    const int stride = (gridDim.x >> 3) * blockDim.x;
    for (int e = (blockIdx.x >> 3) * blockDim.x + threadIdx.x; e < etot;
         e += stride) {
        int dst = (e < er) ? ei[er + e] : (e - er);
        if (dst >= lo && dst < hi) {
            int src = (e < er) ? ei[e] : dst;
            int pos = atomicAdd(&woff[dst], 1);
            colv[pos] = src;
        }
    }
}

__global__ __launch_bounds__(1024) void scanA(const int* __restrict__ deg,
                                              int* __restrict__ escan,
                                              int* __restrict__ bsum, int n) {
    __shared__ int wsum[16], wpre[16];
    const int lane = threadIdx.x & 63, wv = threadIdx.x >> 6;
    const int i = blockIdx.x * 1024 + threadIdx.x;
    int v = (i < n) ? deg[i] : 0;
    int x = v;
#pragma unroll
    for (int off = 1; off < 64; off <<= 1) {
        int y = __shfl_up(x, off, 64);
        if (lane >= off) x += y;
    }
    if (lane == 63) wsum[wv] = x;
    __syncthreads();
    if (wv == 0) {
        int s = (lane < 16) ? wsum[lane] : 0;
#pragma unroll
        for (int off = 1; off < 16; off <<= 1) {
            int y = __shfl_up(s, off, 64);
            if (lane >= off) s += y;
        }
        if (lane < 16) wpre[lane] = s;
    }
    __syncthreads();
    int excl = x - v + (wv ? wpre[wv - 1] : 0);
    if (i < n) escan[i] = excl;
    if (threadIdx.x == 1023) bsum[blockIdx.x] = wpre[15];
}

__global__ __launch_bounds__(1024) void scanB(const int* __restrict__ bsum,
                                              int* __restrict__ bpre, int nb,
                                              int* __restrict__ offs, int n) {
    __shared__ int wsum[16], wpre[16];
    const int lane = threadIdx.x & 63, wv = threadIdx.x >> 6;
    const int i = threadIdx.x;
    int v = (i < nb) ? bsum[i] : 0;
    int x = v;
#pragma unroll
    for (int off = 1; off < 64; off <<= 1) {
        int y = __shfl_up(x, off, 64);
        if (lane >= off) x += y;
    }
    if (lane == 63) wsum[wv] = x;
    __syncthreads();
    if (wv == 0) {
        int s = (lane < 16) ? wsum[lane] : 0;
#pragma unroll
        for (int off = 1; off < 16; off <<= 1) {
            int y = __shfl_up(s, off, 64);
            if (lane >= off) s += y;
        }
        if (lane < 16) wpre[lane] = s;
    }
    __syncthreads();
    if (i < nb) bpre[i] = x - v + (wv ? wpre[wv - 1] : 0);
    if (threadIdx.x == 1023) offs[n] = wpre[15];
}

__global__ void scanC(const int* __restrict__ escan, const int* __restrict__ bpre,
                      int* __restrict__ offs, int* __restrict__ woff, int n) {
    int i = blockIdx.x * 256 + threadIdx.x;
    if (i >= n) return;
    int o = escan[i] + bpre[i >> 10];
    offs[i] = o;
    woff[i] = o;
}

// ---------------------------------------------------------------------------
// Both layers' W -> per-MFMA-fragment bf16 hi/lo layout (one dispatch).
// ---------------------------------------------------------------------------
__global__ void cvt_w2(const float* __restrict__ Wl0, const float* __restrict__ Wr0,
                       const float* __restrict__ Wl1, const float* __restrict__ Wr1,
                       ushort* __restrict__ Whi, ushort* __restrict__ Wlo) {
    int t = blockIdx.x * 256 + threadIdx.x;     // 0..65535
    int layer = t >> 15;
    int i = t & 32767;
    int colblk = i >> 11;
    int ks = (i >> 9) & 3;
    int lane = (i >> 3) & 63;
    int j = i & 7;
    int col = colblk * 16 + (lane & 15);
    int k = ks * 32 + (lane >> 4) * 8 + j;
    const float* Wl = layer ? Wl1 : Wl0;
    const float* Wr = layer ? Wr1 : Wr0;
    float v = (col < 128) ? Wl[(size_t)k * 128 + col]
                          : Wr[(size_t)k * 128 + (col - 128)];
    ushort h = bf16_rne(v);
    Whi[t] = h;
    Wlo[t] = bf16_rne(v - bf16_to_f(h));
}

// ---------------------------------------------------------------------------
// Dual GEMM, 2 MFMA per fragment — UNCHANGED (clean A/B for profiling).
// ---------------------------------------------------------------------------
template <bool ABF16>
__global__ __launch_bounds__(256) void gemm_mfma(
    const void* __restrict__ Xin,
    const ushort* __restrict__ Wfhi, const ushort* __restrict__ Wflo,
    uint* __restrict__ Olb, uint* __restrict__ Orb, int nrows) {
    __shared__ float4 xs[64 * 32];              // 32 KiB (fp32) / 16 KiB used (bf16)
    const int t = threadIdx.x;
    const int wave = t >> 6, lane = t & 63;
    const int m0 = blockIdx.x * 64;
    if (ABF16) {
        const uint4* Xv = (const uint4*)Xin + (size_t)m0 * 16;
        uint4* xsb = (uint4*)xs;
#pragma unroll
        for (int i = 0; i < 4; ++i) {
            int idx = i * 256 + t;
            int row = idx >> 4, kc = idx & 15;
            uint4 v = {0u, 0u, 0u, 0u};
            if (m0 + row < nrows) v = Xv[idx];
            xsb[row * 16 + (kc ^ (row & 7))] = v;
        }
    } else {
        const float4* Xv = (const float4*)Xin + (size_t)m0 * 32;
#pragma unroll
        for (int i = 0; i < 8; ++i) {
            int idx = i * 256 + t;
            int row = idx >> 5, kc = idx & 31;
            float4 v = {0.f, 0.f, 0.f, 0.f};
            if (m0 + row < nrows) v = Xv[idx];
            xs[row * 32 + (kc ^ (row & 7))] = v;
        }
    }
    __syncthreads();

    const int lrow = lane & 15;
    const int lkc = (lane >> 4) * 2;
    f32x4 acc[4][4];
#pragma unroll
    for (int mt = 0; mt < 4; ++mt)
#pragma unroll
        for (int nt = 0; nt < 4; ++nt) acc[mt][nt] = (f32x4){0.f, 0.f, 0.f, 0.f};

#pragma unroll 1
    for (int ks = 0; ks < 4; ++ks) {
        short8 ahi[4];
#pragma unroll
        for (int mt = 0; mt < 4; ++mt) {
            const int row = mt * 16 + lrow;
            if (ABF16) {
                const int slot = ks * 4 + (lane >> 4);
                uint4 w = ((const uint4*)xs)[row * 16 + (slot ^ (row & 7))];
                ahi[mt] = *(const short8*)&w;
            } else {
                const int kc0 = ks * 8 + lkc;
                float4 v0 = xs[row * 32 + (kc0 ^ (row & 7))];
                float4 v1 = xs[row * 32 + ((kc0 + 1) ^ (row & 7))];
                uint4 q;
                q.x = cvt_pk_bf16(v0.x, v0.y);
                q.y = cvt_pk_bf16(v0.z, v0.w);
                q.z = cvt_pk_bf16(v1.x, v1.y);
                q.w = cvt_pk_bf16(v1.z, v1.w);
                ahi[mt] = *(const short8*)&q;
            }
        }
#pragma unroll
        for (int nt = 0; nt < 4; ++nt) {
            size_t off = (((size_t)(wave * 4 + nt) * 4 + ks) * 64 + lane) * 8;
            short8 bhi = *(const short8*)&Wfhi[off];
            short8 blo = *(const short8*)&Wflo[off];
#pragma unroll
            for (int mt = 0; mt < 4; ++mt) {
                acc[mt][nt] = __builtin_amdgcn_mfma_f32_16x16x32_bf16(
                    ahi[mt], blo, acc[mt][nt], 0, 0, 0);
                acc[mt][nt] = __builtin_amdgcn_mfma_f32_16x16x32_bf16(
                    ahi[mt], bhi, acc[mt][nt], 0, 0, 0);
            }
        }
    }
    // Epilogue: C/D frag col=lane&15, row=(lane>>4)*4+i; shfl_xor(1) pairs cols.
    uint* __restrict__ O = (wave < 2) ? Olb : Orb;
    const int cbase = (wave * 64) & 127;
    const int crow0 = (lane >> 4) * 4;
    const bool evn = (lane & 1) == 0;
#pragma unroll
    for (int mt = 0; mt < 4; ++mt) {
#pragma unroll
        for (int i = 0; i < 4; ++i) {
            const int row = m0 + mt * 16 + crow0 + i;
#pragma unroll
            for (int nt = 0; nt < 4; ++nt) {
                float val = acc[mt][nt][i];
                float pv = __shfl_xor(val, 1);
                uint pk = (uint)bf16_rne(val) | ((uint)bf16_rne(pv) << 16);
                if (evn && row < nrows) {
                    const int col = cbase + nt * 16 + lrow;
                    O[(size_t)row * 64 + (col >> 1)] = pk;
                }
            }
        }
    }
}

// ---------------------------------------------------------------------------
// Fused GATv2 agg + bias + ELU + residual + LayerNorm. One wave per node.
// Head reduce via DPP adds (quad_perm/row_half_mirror) — zero DS ops per
// edge (was 3 ds_swizzle with lgkmcnt waits). LN reduce: 4 DPP levels +
// 2 shuffles (xor16/32, per-node only).
// ---------------------------------------------------------------------------
template <bool RBF16, bool OBF16>
__global__ __launch_bounds__(256) void gat_agg(
    const uint* __restrict__ xl, const uint* __restrict__ xr,
    const int* __restrict__ offs, const int* __restrict__ colv,
    const float* __restrict__ att,
    const float* __restrict__ bias, const float* __restrict__ gamma,
    const float* __restrict__ beta, const void* __restrict__ resid,
    void* __restrict__ out, int nnode) {
    const int lane = threadIdx.x & 63;
    const int wid = __builtin_amdgcn_readfirstlane(threadIdx.x >> 6);
    const int wave0 = blockIdx.x * 4 + wid;
    const int wstride = gridDim.x * 4;
    const f32x2 att2 = ((const f32x2*)att)[lane];
    const f32x2 b2 = ((const f32x2*)bias)[lane];
    const f32x2 g2 = ((const f32x2*)gamma)[lane];
    const f32x2 be2 = ((const f32x2*)beta)[lane];
    for (int gid = wave0; gid < nnode; gid += wstride) {
        const uint xru = __builtin_nontemporal_load(xr + (size_t)gid * 64 + lane);
        const f32x2 xr2 = unpk(xru);
        float den = 0.f;
        f32x2 acc = {0.f, 0.f};
        int e = offs[gid];
        const int e1 = offs[gid + 1];
        for (; e + 4 <= e1; e += 4) {
            int s[4];
#pragma unroll
            for (int k = 0; k < 4; ++k)
                s[k] = __builtin_amdgcn_readfirstlane(colv[e + k]);
            uint u[4];
#pragma unroll
            for (int k = 0; k < 4; ++k) u[k] = xl[(size_t)s[k] * 64 + lane];
#pragma unroll
            for (int k = 0; k < 4; ++k) {
                f32x2 a = unpk(u[k]);
                f32x2 m = a + xr2;
                f32x2 l = m * LEAKY;
                m.x = fmaxf(m.x, l.x); m.y = fmaxf(m.y, l.y);
                f32x2 t = m * att2;
                float p = t.x + t.y;
                p = dpp_radd<0xB1>(p);     // xor 1 (quad_perm [1,0,3,2])
                p = dpp_radd<0x4E>(p);     // xor 2 (quad_perm [2,3,0,1])
                p = dpp_radd<0x141>(p);    // xor 4 (row_half_mirror, quad-uniform)
                float ex = __expf(p);
                den += ex;
                acc += a * ex;
            }
        }
        for (; e < e1; ++e) {
            int s0 = __builtin_amdgcn_readfirstlane(colv[e]);
            uint u0 = xl[(size_t)s0 * 64 + lane];
            f32x2 a0 = unpk(u0);
            f32x2 m0 = a0 + xr2;
            f32x2 l0 = m0 * LEAKY;
            m0.x = fmaxf(m0.x, l0.x); m0.y = fmaxf(m0.y, l0.y);
            f32x2 t0 = m0 * att2;
            float p0 = t0.x + t0.y;
            p0 = dpp_radd<0xB1>(p0);
            p0 = dpp_radd<0x4E>(p0);
            p0 = dpp_radd<0x141>(p0);
            float ex0 = __expf(p0);
            den += ex0;
            acc += a0 * ex0;
        }
        const float inv_den = 1.f / den;
        f32x2 v = acc * inv_den + b2;
        v.x = v.x > 0.f ? v.x : expm1f(v.x);     // ELU (alpha=1)
        v.y = v.y > 0.f ? v.y : expm1f(v.y);
        f32x2 r2;
        if (RBF16) {
            uint ru = __builtin_nontemporal_load(
                (const uint*)resid + (size_t)gid * 64 + lane);
            r2 = unpk(ru);
        } else {
            r2 = __builtin_nontemporal_load(
                (const f32x2*)resid + (size_t)gid * 64 + lane);
        }
        f32x2 tv = v + r2;
        float s = tv.x + tv.y, ss = tv.x * tv.x + tv.y * tv.y;
        s = dpp_radd<0xB1>(s);   ss = dpp_radd<0xB1>(ss);    // xor 1
        s = dpp_radd<0x4E>(s);   ss = dpp_radd<0x4E>(ss);    // xor 2
        s = dpp_radd<0x141>(s);  ss = dpp_radd<0x141>(ss);   // xor 4
        s = dpp_radd<0x140>(s);  ss = dpp_radd<0x140>(ss);   // xor 8 (row_mirror)
        s += __shfl_xor(s, 16);  ss += __shfl_xor(ss, 16);
        s += __shfl_xor(s, 32);  ss += __shfl_xor(ss, 32);
        const float mu = s * 0.0078125f;
        const float var = ss * 0.0078125f - mu * mu;
        const float iv = rsqrtf(var + LN_EPS);
        f32x2 o = (tv - mu) * iv * g2 + be2;
        if (OBF16) {
            uint po = (uint)bf16_rne(o.x) | ((uint)bf16_rne(o.y) << 16);
            __builtin_nontemporal_store(po, (uint*)out + (size_t)gid * 64 + lane);
        } else {
            __builtin_nontemporal_store(o, (f32x2*)out + (size_t)gid * 64 + lane);
        }
    }
}

// ---------------------------------------------------------------------------
extern "C" void kernel_launch(void* const* d_in, const int* in_sizes, int n_in,
                              void* d_out, int out_size, void* d_ws, size_t ws_size,
                              hipStream_t stream) {
    const float* x   = (const float*)d_in[0];
    const int*   ei  = (const int*)d_in[1];
    const float* Wl0 = (const float*)d_in[2];
    const float* Wr0 = (const float*)d_in[3];
    const float* at0 = (const float*)d_in[4];
    const float* b0  = (const float*)d_in[5];
    const float* g0  = (const float*)d_in[6];
    const float* be0 = (const float*)d_in[7];
    const float* Wl1 = (const float*)d_in[8];
    const float* Wr1 = (const float*)d_in[9];
    const float* at1 = (const float*)d_in[10];
    const float* b1  = (const float*)d_in[11];
    const float* g1  = (const float*)d_in[12];
    const float* be1 = (const float*)d_in[13];

    const int NF = in_sizes[0];        // N*128
    const int n  = NF / 128;           // nodes
    const int er = in_sizes[1] / 2;    // raw edges
    const int etot = er + n;           // + self-loops
    const int nb = (n + 1023) / 1024;  // scan blocks

    uint* A     = (uint*)d_ws;         // xl bf16-packed (N*64 uints)
    uint* B     = A + (size_t)NF / 2;  // xr bf16-packed
    uint* C1    = B + (size_t)NF / 2;  // layer-1 output, bf16-packed
    ushort* Whi = (ushort*)(C1 + (size_t)NF / 2);  // [2][32768] bf16 hi
    ushort* Wlo = Whi + 65536;                     // [2][32768] bf16 lo
    int* deg    = (int*)(Wlo + 65536);
    int* woff   = deg + n;
    int* offs   = woff + n;
    int* escan  = offs + (n + 4);      // n+1 used; +4 keeps colv 16B-aligned
    int* bsum   = escan + n;
    int* bpre   = bsum + 1024;
    int* colv   = bpre + 1024;
    float* C    = (float*)d_out;       // final fp32 output

    // ---- CSR build (XCD-partitioned) + both W conversions ----
    (void)hipMemsetAsync(deg, 0, (size_t)n * sizeof(int), stream);
    hist_part<<<2048, 256, 0, stream>>>(ei, er, etot, n, deg);
    scanA<<<nb, 1024, 0, stream>>>(deg, escan, bsum, n);
    scanB<<<1, 1024, 0, stream>>>(bsum, bpre, nb, offs, n);
    scanC<<<(n + 255) / 256, 256, 0, stream>>>(escan, bpre, offs, woff, n);
    fill_part<<<2048, 256, 0, stream>>>(ei, er, etot, n, woff, colv);
    cvt_w2<<<256, 256, 0, stream>>>(Wl0, Wr0, Wl1, Wr1, Whi, Wlo);

    const int gblk = (n + 63) / 64;

    // ---- layer 1: fp32 x -> A,B ; agg -> C1 (bf16 packed), resid = x fp32 ----
    gemm_mfma<false><<<gblk, 256, 0, stream>>>(x, Whi, Wlo, A, B, n);
    gat_agg<false, true><<<2048, 256, 0, stream>>>(
        A, B, offs, colv, at0, b0, g0, be0, x, C1, n);
    // ---- layer 2: bf16 C1 -> A,B ; agg -> d_out fp32, resid = C1 bf16 ----
    gemm_mfma<true><<<gblk, 256, 0, stream>>>(C1, Whi + 32768, Wlo + 32768,
                                              A, B, n);
    gat_agg<true, false><<<2048, 256, 0, stream>>>(
        A, B, offs, colv, at1, b1, g1, be1, C1, C, n);
}